// Round 4
// baseline (429.117 us; speedup 1.0000x reference)
//
#include <hip/hip_runtime.h>
#include <math.h>

#define TT 2048   // tokens
#define HH 1024   // hidden
#define EE 8      // experts
#define II 2048   // intermediate
#define N1 4096   // 2*II
#define ALPHA 1.702f
#define LIMIT 7.0f

typedef __attribute__((ext_vector_type(8))) short short8;
typedef __attribute__((ext_vector_type(4))) float floatx4;
typedef __attribute__((ext_vector_type(4))) unsigned int uintx4;

__device__ __forceinline__ short f2bf(float f) {
  union { float f; unsigned u; } v; v.f = f;
  unsigned r = (v.u + 0x7fffu + ((v.u >> 16) & 1u)) >> 16;
  return (short)r;
}
// 2x f32 -> packed bf16 (RNE), lo in low 16 bits
__device__ __forceinline__ unsigned cvt2(float lo, float hi) {
  unsigned r;
  asm("v_cvt_pk_bf16_f32 %0, %1, %2" : "=v"(r) : "v"(lo), "v"(hi));
  return r;
}
// async global->LDS DMA, 16B per lane; global addr per-lane, LDS dest uniform
__device__ __forceinline__ void gload16(const void* g, void* l) {
  __builtin_amdgcn_global_load_lds(
      (const __attribute__((address_space(1))) unsigned int*)g,
      (__attribute__((address_space(3))) unsigned int*)l, 16, 0, 0);
}

// ---------------- prepass: x f32 -> bf16 ----------------
__global__ __launch_bounds__(256) void convert_x(const float* __restrict__ x,
                                                 unsigned short* __restrict__ xb) {
  const int id = blockIdx.x * 256 + threadIdx.x;  // TT*HH/8 total
  const float4 a = ((const float4*)x)[id * 2];
  const float4 b = ((const float4*)x)[id * 2 + 1];
  uintx4 w;
  w[0] = cvt2(a.x, a.y); w[1] = cvt2(a.z, a.w);
  w[2] = cvt2(b.x, b.y); w[3] = cvt2(b.z, b.w);
  ((uintx4*)xb)[id] = w;
}

// ---------------- prepass: weight [E][K][N] f32 -> [E][N][K] bf16 ----------------
__global__ __launch_bounds__(256) void transpose_bf16(
    const float* __restrict__ src, unsigned short* __restrict__ dst,
    const int K, const int N) {
  const int e = blockIdx.z;
  const int n0 = blockIdx.x * 64, k0 = blockIdx.y * 64;
  __shared__ float tile[64][68];
  const float* s = src + (size_t)e * K * N;
  unsigned short* d = dst + (size_t)e * N * K;
  const int t = threadIdx.x;
  const int nq = t & 15, kr = t >> 4;
#pragma unroll
  for (int r = 0; r < 4; r++) {
    const int k = r * 16 + kr;
    const float4 v = *(const float4*)(s + (size_t)(k0 + k) * N + n0 + nq * 4);
    tile[k][nq * 4 + 0] = v.x; tile[k][nq * 4 + 1] = v.y;
    tile[k][nq * 4 + 2] = v.z; tile[k][nq * 4 + 3] = v.w;
  }
  __syncthreads();
  const int n = t >> 2, ks = (t & 3) * 16;
  unsigned short* orow = d + (size_t)(n0 + n) * K + k0 + ks;
  uintx4 w0, w1;
#pragma unroll
  for (int m = 0; m < 4; m++)
    w0[m] = cvt2(tile[ks + 2 * m][n], tile[ks + 2 * m + 1][n]);
#pragma unroll
  for (int m = 0; m < 4; m++)
    w1[m] = cvt2(tile[ks + 8 + 2 * m][n], tile[ks + 9 + 2 * m][n]);
  *(uintx4*)orow = w0;
  *(uintx4*)(orow + 8) = w1;
}

// ---------------- router: logits -> softmax -> top2 ----------------
__global__ __launch_bounds__(256) void router_kernel(
    const float* __restrict__ x, const float* __restrict__ rw,
    const float* __restrict__ rb, int* __restrict__ topk_idx,
    float* __restrict__ topk_w) {
  const int t = blockIdx.x;
  const float* xr = x + (size_t)t * HH;
  const int lane = threadIdx.x & 63;
  const int wave = threadIdx.x >> 6;
  float xv[16];
#pragma unroll
  for (int i = 0; i < 16; i++) xv[i] = xr[lane + i * 64];
  __shared__ float logits[EE];
#pragma unroll
  for (int ee = 0; ee < 2; ee++) {
    const int e = wave * 2 + ee;
    const float* wr = rw + (size_t)e * HH;
    float s = 0.f;
#pragma unroll
    for (int i = 0; i < 16; i++) s += xv[i] * wr[lane + i * 64];
#pragma unroll
    for (int off = 32; off > 0; off >>= 1) s += __shfl_down(s, off, 64);
    if (lane == 0) logits[e] = s + rb[e];
  }
  __syncthreads();
  if (threadIdx.x == 0) {
    float l[EE], sc[EE];
    float mx = -3.4e38f;
    for (int i = 0; i < EE; i++) { l[i] = logits[i]; mx = fmaxf(mx, l[i]); }
    float sum = 0.f;
    for (int i = 0; i < EE; i++) { sc[i] = expf(l[i] - mx); sum += sc[i]; }
    const float inv = 1.f / sum;
    int i0 = 0;
    for (int i = 1; i < EE; i++) if (sc[i] > sc[i0]) i0 = i;
    int i1 = (i0 == 0) ? 1 : 0;
    for (int i = 0; i < EE; i++) if (i != i0 && sc[i] > sc[i1]) i1 = i;
    topk_idx[t * 2 + 0] = i0;
    topk_idx[t * 2 + 1] = i1;
    topk_w[t * 2 + 0] = sc[i0] * inv;
    topk_w[t * 2 + 1] = sc[i1] * inv;
  }
}

// ---------------- token->expert compaction ----------------
__global__ void assign_kernel(const int* __restrict__ topk_idx,
                              int* __restrict__ counts, int* __restrict__ rows) {
  const int id = blockIdx.x * blockDim.x + threadIdx.x;
  if (id >= TT * 2) return;
  const int e = topk_idx[id];
  const int slot = atomicAdd(&counts[e], 1);
  rows[e * TT + slot] = id;  // entry = t*2 + k
}

// ---- GEMM1 (m97-structure) + fused GLU: act[ent][i] ----
// 4 waves, tile 128 rows x (64 gate cols + 64 up cols), BK=32.
// global_load_lds dbuf, vmcnt(4) counted, 2 barriers/k-step, 16 MFMA/wave.
__global__ __launch_bounds__(256, 4) void gemm_gu(
    const unsigned short* __restrict__ xb, const unsigned short* __restrict__ gupt,
    const float* __restrict__ gub, const int* __restrict__ counts,
    const int* __restrict__ rows, unsigned short* __restrict__ act) {
  const int e = blockIdx.z, mtile = blockIdx.y, ntile = blockIdx.x;
  const int count = counts[e];
  if (mtile * 128 >= count) return;
  const int* rl = rows + e * TT + mtile * 128;
  __shared__ __align__(16) char smem[33280];
  unsigned short* As = (unsigned short*)smem;            // [2][4096] bf16
  unsigned short* Bs = (unsigned short*)(smem + 16384);  // [2][4096] bf16
  float* glds = (float*)smem;                            // [128][65] epilogue overlay
  const int tid = threadIdx.x;
  const int lane = tid & 63, wave = tid >> 6;
  const int wm = (wave & 1) << 6, wn = (wave >> 1) << 6;
  const int quad = lane >> 4, r16 = lane & 15;

  // staging: instr q=wave*2+r covers rows q*16+(lane>>2), 16B at (lane&3)*16
  const int lrow = lane >> 2, lko = (lane & 3) * 8;
  const int q0 = wave * 2, q1 = q0 + 1;
  const int row0 = q0 * 16 + lrow, row1 = q1 * 16 + lrow;
  const int last = count - 1 - mtile * 128;
  const int cr0 = row0 <= last ? row0 : last;
  const int cr1 = row1 <= last ? row1 : last;
  const unsigned short* pA0 = xb + (size_t)(rl[cr0] >> 1) * HH + lko;
  const unsigned short* pA1 = xb + (size_t)(rl[cr1] >> 1) * HH + lko;
  const int bn0 = (row0 < 64) ? (ntile * 64 + row0) : (II + ntile * 64 + row0 - 64);
  const int bn1 = (row1 < 64) ? (ntile * 64 + row1) : (II + ntile * 64 + row1 - 64);
  const unsigned short* pB0 = gupt + (size_t)e * N1 * HH + (size_t)bn0 * HH + lko;
  const unsigned short* pB1 = gupt + (size_t)e * N1 * HH + (size_t)bn1 * HH + lko;
  unsigned short* dA0 = As + q0 * 512;  // wave-uniform LDS dests
  unsigned short* dA1 = As + q1 * 512;
  unsigned short* dB0 = Bs + q0 * 512;
  unsigned short* dB1 = Bs + q1 * 512;

  floatx4 acc[4][4] = {};
  const int NTK = HH / 32;  // 32

#define STAGE(B, kk) do { \
    const int ko_ = (kk) * 32; \
    gload16(pA0 + ko_, dA0 + (B) * 4096); \
    gload16(pA1 + ko_, dA1 + (B) * 4096); \
    gload16(pB0 + ko_, dB0 + (B) * 4096); \
    gload16(pB1 + ko_, dB1 + (B) * 4096); \
  } while (0)

#define PHASE(B) do { \
    asm volatile("s_waitcnt vmcnt(4)" ::: "memory"); \
    __builtin_amdgcn_s_barrier(); \
    short8 af[4], bf4[4]; \
    _Pragma("unroll") for (int i = 0; i < 4; i++) \
      af[i] = *(const short8*)(As + (B) * 4096 + (wm + i * 16 + r16) * 32 + quad * 8); \
    _Pragma("unroll") for (int j = 0; j < 4; j++) \
      bf4[j] = *(const short8*)(Bs + (B) * 4096 + (wn + j * 16 + r16) * 32 + quad * 8); \
    asm volatile("s_waitcnt lgkmcnt(0)" ::: "memory"); \
    __builtin_amdgcn_sched_barrier(0); \
    __builtin_amdgcn_s_barrier(); \
    { const int ks_ = kn < NTK ? kn : NTK - 1; kn++; STAGE(B, ks_); } \
    __builtin_amdgcn_sched_barrier(0); \
    __builtin_amdgcn_s_setprio(1); \
    _Pragma("unroll") for (int i = 0; i < 4; i++) \
      _Pragma("unroll") for (int j = 0; j < 4; j++) \
        acc[i][j] = __builtin_amdgcn_mfma_f32_16x16x32_bf16(af[i], bf4[j], acc[i][j], 0, 0, 0); \
    __builtin_amdgcn_s_setprio(0); \
  } while (0)

  STAGE(0, 0);
  STAGE(1, 1);
  int kn = 2;
#pragma unroll 1
  for (int t = 0; t < NTK; t += 2) {
    PHASE(0);
    PHASE(1);
  }
  asm volatile("s_waitcnt vmcnt(0)" ::: "memory");
  __builtin_amdgcn_s_barrier();

  // epilogue: gate waves (wn==0) -> glu to LDS; up waves -> act bf16
  const int colbase = ntile * 64;
  if (wn == 0) {
#pragma unroll
    for (int j = 0; j < 4; j++) {
      const int c = j * 16 + r16;
      const float gb = gub[e * N1 + colbase + c];
#pragma unroll
      for (int i = 0; i < 4; i++)
#pragma unroll
        for (int reg = 0; reg < 4; reg++) {
          const int rr = wm + i * 16 + quad * 4 + reg;
          float g = acc[i][j][reg] + gb;
          g = fminf(g, LIMIT);
          glds[rr * 65 + c] = g / (1.f + expf(-g * ALPHA));
        }
    }
  }
  __builtin_amdgcn_s_barrier();
  if (wn == 64) {
#pragma unroll
    for (int j = 0; j < 4; j++) {
      const int c = j * 16 + r16;
      const float ub = gub[e * N1 + II + colbase + c];
#pragma unroll
      for (int i = 0; i < 4; i++)
#pragma unroll
        for (int reg = 0; reg < 4; reg++) {
          const int rr = wm + i * 16 + quad * 4 + reg;
          if (mtile * 128 + rr < count) {
            float u = acc[i][j][reg] + ub;
            u = fminf(fmaxf(u, -LIMIT), LIMIT);
            const float glu = glds[rr * 65 + c];
            act[(size_t)rl[rr] * II + colbase + c] = (unsigned short)f2bf((u + 1.f) * glu);
          }
        }
    }
  }
#undef STAGE
#undef PHASE
}

// ---- GEMM2 (m97-structure): act bf16 x dp_t bf16 -> dout f32, split-K=4 ----
__global__ __launch_bounds__(256, 4) void gemm_down(
    const unsigned short* __restrict__ act, const unsigned short* __restrict__ dpt,
    const float* __restrict__ db, const int* __restrict__ counts,
    const int* __restrict__ rows, float* __restrict__ dout) {
  const int e = blockIdx.z >> 2, kc = blockIdx.z & 3;
  const int mtile = blockIdx.y, ntile = blockIdx.x;
  const int count = counts[e];
  if (mtile * 128 >= count) return;
  const int kb = kc * (II / 4);  // 512-wide K chunk
  const int* rl = rows + e * TT + mtile * 128;
  __shared__ __align__(16) char smem[32768];
  unsigned short* As = (unsigned short*)smem;
  unsigned short* Bs = (unsigned short*)(smem + 16384);
  const int tid = threadIdx.x;
  const int lane = tid & 63, wave = tid >> 6;
  const int wm = (wave & 1) << 6, wn = (wave >> 1) << 6;
  const int quad = lane >> 4, r16 = lane & 15;

  const int lrow = lane >> 2, lko = (lane & 3) * 8;
  const int q0 = wave * 2, q1 = q0 + 1;
  const int row0 = q0 * 16 + lrow, row1 = q1 * 16 + lrow;
  const int last = count - 1 - mtile * 128;
  const int cr0 = row0 <= last ? row0 : last;
  const int cr1 = row1 <= last ? row1 : last;
  const unsigned short* pA0 = act + (size_t)rl[cr0] * II + kb + lko;
  const unsigned short* pA1 = act + (size_t)rl[cr1] * II + kb + lko;
  const unsigned short* pB0 = dpt + (size_t)e * HH * II + (size_t)(ntile * 128 + row0) * II + kb + lko;
  const unsigned short* pB1 = dpt + (size_t)e * HH * II + (size_t)(ntile * 128 + row1) * II + kb + lko;
  unsigned short* dA0 = As + q0 * 512;
  unsigned short* dA1 = As + q1 * 512;
  unsigned short* dB0 = Bs + q0 * 512;
  unsigned short* dB1 = Bs + q1 * 512;

  floatx4 acc[4][4] = {};
  const int NTK = (II / 4) / 32;  // 16

#define STAGE(B, kk) do { \
    const int ko_ = (kk) * 32; \
    gload16(pA0 + ko_, dA0 + (B) * 4096); \
    gload16(pA1 + ko_, dA1 + (B) * 4096); \
    gload16(pB0 + ko_, dB0 + (B) * 4096); \
    gload16(pB1 + ko_, dB1 + (B) * 4096); \
  } while (0)

#define PHASE(B) do { \
    asm volatile("s_waitcnt vmcnt(4)" ::: "memory"); \
    __builtin_amdgcn_s_barrier(); \
    short8 af[4], bf4[4]; \
    _Pragma("unroll") for (int i = 0; i < 4; i++) \
      af[i] = *(const short8*)(As + (B) * 4096 + (wm + i * 16 + r16) * 32 + quad * 8); \
    _Pragma("unroll") for (int j = 0; j < 4; j++) \
      bf4[j] = *(const short8*)(Bs + (B) * 4096 + (wn + j * 16 + r16) * 32 + quad * 8); \
    asm volatile("s_waitcnt lgkmcnt(0)" ::: "memory"); \
    __builtin_amdgcn_sched_barrier(0); \
    __builtin_amdgcn_s_barrier(); \
    { const int ks_ = kn < NTK ? kn : NTK - 1; kn++; STAGE(B, ks_); } \
    __builtin_amdgcn_sched_barrier(0); \
    __builtin_amdgcn_s_setprio(1); \
    _Pragma("unroll") for (int i = 0; i < 4; i++) \
      _Pragma("unroll") for (int j = 0; j < 4; j++) \
        acc[i][j] = __builtin_amdgcn_mfma_f32_16x16x32_bf16(af[i], bf4[j], acc[i][j], 0, 0, 0); \
    __builtin_amdgcn_s_setprio(0); \
  } while (0)

  STAGE(0, 0);
  STAGE(1, 1);
  int kn = 2;
#pragma unroll 1
  for (int t = 0; t < NTK; t += 2) {
    PHASE(0);
    PHASE(1);
  }
  asm volatile("s_waitcnt vmcnt(0)" ::: "memory");
  __builtin_amdgcn_s_barrier();

  float* dc = dout + (size_t)kc * ((size_t)TT * 2 * HH);
#pragma unroll
  for (int i = 0; i < 4; i++) {
#pragma unroll
    for (int reg = 0; reg < 4; reg++) {
      const int rr = wm + i * 16 + quad * 4 + reg;
      if (mtile * 128 + rr < count) {
        const int ent = rl[rr];
        float* orow = dc + (size_t)ent * HH + ntile * 128;
#pragma unroll
        for (int j = 0; j < 4; j++) {
          const int c = wn + j * 16 + r16;
          float v = acc[i][j][reg];
          if (kc == 0) v += db[e * HH + ntile * 128 + c];
          orow[c] = v;
        }
      }
    }
  }
#undef STAGE
#undef PHASE
}

// ---------------- combine: out = w0*Σc d[c][2t] + w1*Σc d[c][2t+1] ----------------
__global__ void combine_kernel(const float* __restrict__ dout,
                               const float* __restrict__ tw,
                               float* __restrict__ out) {
  const int id = blockIdx.x * blockDim.x + threadIdx.x;
  const int t = id >> 8;
  const int h = (id & 255) * 4;
  const float w0 = tw[t * 2], w1 = tw[t * 2 + 1];
  const size_t CH = (size_t)TT * 2 * HH;
  const size_t r0 = (size_t)(2 * t) * HH + h;
  const size_t r1 = (size_t)(2 * t + 1) * HH + h;
  float4 a = {0.f, 0.f, 0.f, 0.f}, b = {0.f, 0.f, 0.f, 0.f};
#pragma unroll
  for (int c = 0; c < 4; c++) {
    const float4 va = *(const float4*)(dout + c * CH + r0);
    const float4 vb = *(const float4*)(dout + c * CH + r1);
    a.x += va.x; a.y += va.y; a.z += va.z; a.w += va.w;
    b.x += vb.x; b.y += vb.y; b.z += vb.z; b.w += vb.w;
  }
  float4 o;
  o.x = w0 * a.x + w1 * b.x;
  o.y = w0 * a.y + w1 * b.y;
  o.z = w0 * a.z + w1 * b.z;
  o.w = w0 * a.w + w1 * b.w;
  *(float4*)(out + (size_t)t * HH + h) = o;
}

extern "C" void kernel_launch(void* const* d_in, const int* in_sizes, int n_in,
                              void* d_out, int out_size, void* d_ws, size_t ws_size,
                              hipStream_t stream) {
  const float* x   = (const float*)d_in[0];
  const float* rw  = (const float*)d_in[1];
  const float* rb  = (const float*)d_in[2];
  const float* gup = (const float*)d_in[3];
  const float* gub = (const float*)d_in[4];
  const float* dp  = (const float*)d_in[5];
  const float* db  = (const float*)d_in[6];
  float* out = (float*)d_out;

  char* ws = (char*)d_ws;
  int*   topk_idx = (int*)(ws + 0);                        // 16 KB
  float* topk_w   = (float*)(ws + 16384);                  // 16 KB
  int*   counts   = (int*)(ws + 32768);                    // 256 B
  int*   rows     = (int*)(ws + 33024);                    // 64 KB
  unsigned short* xb   = (unsigned short*)(ws + 131072);               // 4 MB
  unsigned short* gupt = (unsigned short*)(ws + 4325376);              // 67.1 MB
  unsigned short* dpt  = (unsigned short*)(ws + 71434240);             // 33.6 MB
  unsigned short* act  = (unsigned short*)(ws + 104988672);            // 16.8 MB
  float* dout = (float*)(ws + 4325376);  // aliases gupt (dead after gemm_gu)

  convert_x<<<TT * HH / 8 / 256, 256, 0, stream>>>(x, xb);
  transpose_bf16<<<dim3(N1 / 64, HH / 64, EE), 256, 0, stream>>>(gup, gupt, HH, N1);
  transpose_bf16<<<dim3(HH / 64, II / 64, EE), 256, 0, stream>>>(dp, dpt, II, HH);
  router_kernel<<<TT, 256, 0, stream>>>(x, rw, rb, topk_idx, topk_w);
  hipMemsetAsync(counts, 0, 64, stream);
  assign_kernel<<<(TT * 2 + 255) / 256, 256, 0, stream>>>(topk_idx, counts, rows);
  gemm_gu<<<dim3(II / 64, TT / 128, EE), 256, 0, stream>>>(xb, gupt, gub, counts, rows, act);
  gemm_down<<<dim3(HH / 128, TT / 128, EE * 4), 256, 0, stream>>>(act, dpt, db, counts, rows, dout);
  combine_kernel<<<(TT * HH / 4) / 256, 256, 0, stream>>>(dout, topk_w, out);
}